// Round 9
// baseline (206.566 us; speedup 1.0000x reference)
//
#include <hip/hip_runtime.h>
#include <hip/hip_fp16.h>
#include <math.h>

#define NN    50000
#define NE0   800000
#define NE    850000
#define INDIM 128
#define HID   64
#define OUTD  40

#define BINB  256          // bin role blocks
#define G1B   782          // gemm1 role blocks

#define NCAP  64           // per-node edge slab capacity (in-deg ~ Poi(16)+1; 64 > 8 sigma)

typedef unsigned short u16;

// ---------------------------------------------------------------- dispatch A: bin-scatter (blocks 0..255) || GEMM1 (blocks 256..1037)
// bin role: direct per-node CSR build — one global atomic + one u16 scatter
// per edge. Replaces the whole bucket+csr pipeline (R8 lesson: no redundant
// re-derivation). gemm1 role: R7-proven (x staged in LDS, W1 direct L1-hot).
__global__ __launch_bounds__(256, 4) void k_binG1(
    const int* __restrict__ ei, int* __restrict__ ncur, u16* __restrict__ nlist,
    const float* __restrict__ x, const float* __restrict__ W1,
    const float* __restrict__ a_s, const float* __restrict__ a_d,
    __half* __restrict__ h1h, float* __restrict__ asrc1, float* __restrict__ adst1)
{
    __shared__ __align__(16) float xs[64 * 132];   // 33.8 KB (gemm1 role only)
    const int tid = threadIdx.x;

    if (blockIdx.x < BINB) {
        // ---------------- bin role: direct scatter ----------------
        const int CH = (NE + BINB - 1) / BINB;     // 3321
        const int e0 = blockIdx.x * CH;
        const int e1 = (e0 + CH < NE) ? e0 + CH : NE;
#pragma unroll 4
        for (int i = e0 + tid; i < e1; i += 256) {
            int src, dst;
            if (i < NE0) { src = ei[i]; dst = ei[NE0 + i]; }
            else         { src = i - NE0; dst = src; }
            int pos = atomicAdd(&ncur[dst], 1);
            if (pos < NCAP) nlist[dst * NCAP + pos] = (u16)src;
        }
        return;
    }

    // ---------------- GEMM1 role (R7 verbatim) ----------------
    const int r0 = (blockIdx.x - BINB) * 64;

    const float4* x4 = (const float4*)x;
#pragma unroll
    for (int i = 0; i < 8; ++i) {
        int idx = tid + i * 256;           // 0..2047
        int row = idx >> 5;                // 32 float4 per row
        int k4  = idx & 31;
        int nr = r0 + row;
        float4 v = make_float4(0.f, 0.f, 0.f, 0.f);
        if (nr < NN) v = x4[(size_t)nr * 32 + k4];
        *(float4*)&xs[row * 132 + k4 * 4] = v;
    }
    __syncthreads();

    const int rg = tid >> 4;               // 0..15 (4 rows each)
    const int cg = tid & 15;
    const int c4 = cg * 4;
    const float as0 = a_s[c4], as1v = a_s[c4+1], as2v = a_s[c4+2], as3v = a_s[c4+3];
    const float ad0 = a_d[c4], ad1v = a_d[c4+1], ad2v = a_d[c4+2], ad3v = a_d[c4+3];

    float acc[4][4];
#pragma unroll
    for (int i = 0; i < 4; ++i)
#pragma unroll
        for (int j = 0; j < 4; ++j) acc[i][j] = 0.f;

#pragma unroll 4
    for (int k4 = 0; k4 < 32; ++k4) {
        float4 xv[4];
#pragma unroll
        for (int i = 0; i < 4; ++i)
            xv[i] = *(const float4*)&xs[(rg * 4 + i) * 132 + k4 * 4];
        const float* wp = &W1[(k4 * 4) * HID + c4];
        float4 w0 = *(const float4*)(wp);
        float4 w1 = *(const float4*)(wp + HID);
        float4 w2 = *(const float4*)(wp + 2 * HID);
        float4 w3 = *(const float4*)(wp + 3 * HID);
#pragma unroll
        for (int i = 0; i < 4; ++i) {
            acc[i][0] += xv[i].x * w0.x + xv[i].y * w1.x + xv[i].z * w2.x + xv[i].w * w3.x;
            acc[i][1] += xv[i].x * w0.y + xv[i].y * w1.y + xv[i].z * w2.y + xv[i].w * w3.y;
            acc[i][2] += xv[i].x * w0.z + xv[i].y * w1.z + xv[i].z * w2.z + xv[i].w * w3.z;
            acc[i][3] += xv[i].x * w0.w + xv[i].y * w1.w + xv[i].z * w2.w + xv[i].w * w3.w;
        }
    }

#pragma unroll
    for (int i = 0; i < 4; ++i) {
        const int n = r0 + rg * 4 + i;
        if (n < NN) {
            __half2 ha = __floats2half2_rn(acc[i][0], acc[i][1]);
            __half2 hb = __floats2half2_rn(acc[i][2], acc[i][3]);
            *(__half2*)&h1h[(size_t)n * HID + c4]     = ha;
            *(__half2*)&h1h[(size_t)n * HID + c4 + 2] = hb;
        }
        float ps = acc[i][0] * as0 + acc[i][1] * as1v + acc[i][2] * as2v + acc[i][3] * as3v;
        float pd = acc[i][0] * ad0 + acc[i][1] * ad1v + acc[i][2] * ad2v + acc[i][3] * ad3v;
        ps += __shfl_xor(ps, 1); ps += __shfl_xor(ps, 2);
        pd += __shfl_xor(pd, 1); pd += __shfl_xor(pd, 2);
        if ((cg & 3) == 0 && n < NN) {
            int head = cg >> 2;
            asrc1[n * 4 + head] = ps;
            adst1[n * 4 + head] = pd;
        }
    }
}

// ---------------------------------------------------------------- layer-1 aggregate fused with GEMM2 (R7-proven body; slab CSR)
__global__ __launch_bounds__(256) void k_fagg1g2(
    const int* __restrict__ ncur, const u16* __restrict__ nlist,
    const float* __restrict__ asrc1, const float* __restrict__ adst1,
    const __half* __restrict__ h1h, const float* __restrict__ b1,
    const float* __restrict__ W2, const float* __restrict__ a_s2,
    const float* __restrict__ a_d2,
    __half* __restrict__ h2h, float* __restrict__ asrc2, float* __restrict__ adst2)
{
    __shared__ __align__(16) float W2l[HID * OUTD];   // 10.2 KB
    __shared__ __align__(16) float hml[16][72];       // stride 72 (16B-aligned rows)
    __shared__ float s_a2s[OUTD], s_a2d[OUTD];
    __shared__ float s_ps[16], s_pd[16];
    const int tid = threadIdx.x;

    {
        const float4* W24 = (const float4*)W2;
        float4* W2l4 = (float4*)W2l;
        for (int i = tid; i < (HID * OUTD) / 4; i += 256) W2l4[i] = W24[i];
        if (tid < OUTD) { s_a2s[tid] = a_s2[tid]; s_a2d[tid] = a_d2[tid]; }
        if (tid < 16)   { s_ps[tid] = 0.f; s_pd[tid] = 0.f; }
    }

    const int wv = tid >> 6, lane = tid & 63;
    const int g = lane >> 4, li = lane & 15;      // 4 nodes/wave, 16 lanes each
    const int r = wv * 4 + g;                     // 0..15 node slot in block
    const int n = blockIdx.x * 16 + r;            // grid exact: 3125*16 = 50000
    const u16* el = nlist + (size_t)n * NCAP;
    const int s1 = min(ncur[n], NCAP);            // deg >= 1 (self-loop)
    const int hp = li >> 2;                       // head
    const float adst = adst1[n * 4 + hp];
    const int last = s1 - 1;

    float l = 0.f, a0 = 0.f, a1 = 0.f, a2 = 0.f, a3 = 0.f;
    const char* hb = (const char*)h1h;

    int sxA[8];
#pragma unroll
    for (int j = 0; j < 8; ++j) {
        int ix = j;
        sxA[j] = el[ix < s1 ? ix : last];
    }
    for (int t = 0; t < s1; t += 8) {
        float ax[8];
#pragma unroll
        for (int j = 0; j < 8; ++j) ax[j] = asrc1[sxA[j] * 4 + hp];
        uint2 raw[8];
#pragma unroll
        for (int j = 0; j < 8; ++j)
            raw[j] = *(const uint2*)(hb + ((size_t)sxA[j] * 128 + li * 8));
        int sxB[8];
        const int t2 = t + 8;
#pragma unroll
        for (int j = 0; j < 8; ++j) {
            int ix = t2 + j;
            sxB[j] = el[ix < s1 ? ix : last];
        }
#pragma unroll
        for (int j = 0; j < 8; ++j) {
            float e = ax[j] + adst;
            e = (e > 0.f) ? e : 0.2f * e;
            float w = __expf(e);
            w = ((t + j) < s1) ? w : 0.f;
            float2 f0 = __half22float2(*(__half2*)&raw[j].x);
            float2 f1 = __half22float2(*(__half2*)&raw[j].y);
            l  += w;
            a0 += w * f0.x;
            a1 += w * f0.y;
            a2 += w * f1.x;
            a3 += w * f1.y;
        }
#pragma unroll
        for (int j = 0; j < 8; ++j) sxA[j] = sxB[j];
    }

    {
        float rcp = 1.f / l;
        float4 bv = *(const float4*)&b1[li * 4];
        float o0 = fmaxf(a0 * rcp + bv.x, 0.f);
        float o1 = fmaxf(a1 * rcp + bv.y, 0.f);
        float o2 = fmaxf(a2 * rcp + bv.z, 0.f);
        float o3 = fmaxf(a3 * rcp + bv.w, 0.f);
        *(float4*)&hml[r][li * 4] = make_float4(o0, o1, o2, o3);
    }
    __syncthreads();

    // mini-GEMM: 16x64 @ 64x40; 160 threads, one output quad each
    if (tid < 160) {
        const int rr = tid / 10;                  // 0..15
        const int c4 = (tid - rr * 10) * 4;       // 0..36
        float4 acc = make_float4(0.f, 0.f, 0.f, 0.f);
#pragma unroll 4
        for (int k4 = 0; k4 < 16; ++k4) {
            float4 hv = *(const float4*)&hml[rr][k4 * 4];
            const float* wp = &W2l[(k4 * 4) * OUTD + c4];
            float4 w0 = *(const float4*)(wp);
            float4 w1 = *(const float4*)(wp + OUTD);
            float4 w2 = *(const float4*)(wp + 2 * OUTD);
            float4 w3 = *(const float4*)(wp + 3 * OUTD);
            acc.x += hv.x * w0.x + hv.y * w1.x + hv.z * w2.x + hv.w * w3.x;
            acc.y += hv.x * w0.y + hv.y * w1.y + hv.z * w2.y + hv.w * w3.y;
            acc.z += hv.x * w0.z + hv.y * w1.z + hv.z * w2.z + hv.w * w3.z;
            acc.w += hv.x * w0.w + hv.y * w1.w + hv.z * w2.w + hv.w * w3.w;
        }
        const int n2 = blockIdx.x * 16 + rr;
        __half2 ha = __floats2half2_rn(acc.x, acc.y);
        __half2 hc = __floats2half2_rn(acc.z, acc.w);
        uint2 st;
        st.x = *(unsigned*)&ha;
        st.y = *(unsigned*)&hc;
        *(uint2*)((char*)h2h + ((size_t)n2 * 80 + c4 * 2)) = st;
        float ps = acc.x * s_a2s[c4] + acc.y * s_a2s[c4 + 1] + acc.z * s_a2s[c4 + 2] + acc.w * s_a2s[c4 + 3];
        float pd = acc.x * s_a2d[c4] + acc.y * s_a2d[c4 + 1] + acc.z * s_a2d[c4 + 2] + acc.w * s_a2d[c4 + 3];
        atomicAdd(&s_ps[rr], ps);
        atomicAdd(&s_pd[rr], pd);
    }
    __syncthreads();
    if (tid < 16) {
        const int n2 = blockIdx.x * 16 + tid;
        asrc2[n2] = s_ps[tid];
        adst2[n2] = s_pd[tid];
    }
}

// ---------------------------------------------------------------- layer-2 aggregate (R7-proven body; slab CSR) + log_softmax
__global__ __launch_bounds__(256) void k_fagg2(
    const int* __restrict__ ncur, const u16* __restrict__ nlist,
    const float* __restrict__ asrc2, const float* __restrict__ adst2,
    const __half* __restrict__ h2h, const float* __restrict__ b2,
    float* __restrict__ out)
{
    __shared__ float svals[24][OUTD];
    const int wv = threadIdx.x >> 6, lane = threadIdx.x & 63;
    const int g = lane / 10;                       // 0..6 (g==6 idle)
    const int li = lane - g * 10;                  // 0..9
    const bool ga = (g < 6);
    const int n = blockIdx.x * 24 + wv * 6 + (ga ? g : 0);
    const bool valid = ga && (n < NN);
    const u16* el = nlist + (size_t)n * NCAP;
    const int s1 = valid ? min(ncur[n], NCAP) : 0;
    const float adst = valid ? adst2[n] : 0.f;
    const int last = (s1 > 0) ? s1 - 1 : 0;

    float l = 0.f, a0 = 0.f, a1 = 0.f, a2 = 0.f, a3 = 0.f;
    const char* hb = (const char*)h2h;

    int sxA[8];
#pragma unroll
    for (int j = 0; j < 8; ++j) {
        int ix = j;
        sxA[j] = (s1 > 0) ? el[ix < s1 ? ix : last] : 0;
    }
    for (int t = 0; t < s1; t += 8) {
        float ax[8];
#pragma unroll
        for (int j = 0; j < 8; ++j) ax[j] = asrc2[sxA[j]];
        uint2 raw[8];
#pragma unroll
        for (int j = 0; j < 8; ++j)
            raw[j] = *(const uint2*)(hb + ((size_t)sxA[j] * 80 + li * 8));
        int sxB[8];
        const int t2 = t + 8;
#pragma unroll
        for (int j = 0; j < 8; ++j) {
            int ix = t2 + j;
            sxB[j] = el[ix < s1 ? ix : last];
        }
#pragma unroll
        for (int j = 0; j < 8; ++j) {
            float e = ax[j] + adst;
            e = (e > 0.f) ? e : 0.2f * e;
            float w = __expf(e);
            w = ((t + j) < s1) ? w : 0.f;
            float2 f0 = __half22float2(*(__half2*)&raw[j].x);
            float2 f1 = __half22float2(*(__half2*)&raw[j].y);
            l  += w;
            a0 += w * f0.x;
            a1 += w * f0.y;
            a2 += w * f1.x;
            a3 += w * f1.y;
        }
#pragma unroll
        for (int j = 0; j < 8; ++j) sxA[j] = sxB[j];
    }
    if (valid) {
        float rcp = 1.f / l;
        float4 bv = *(const float4*)&b2[li * 4];
        int r = wv * 6 + g;
        svals[r][li * 4]     = a0 * rcp + bv.x;
        svals[r][li * 4 + 1] = a1 * rcp + bv.y;
        svals[r][li * 4 + 2] = a2 * rcp + bv.z;
        svals[r][li * 4 + 3] = a3 * rcp + bv.w;
    }
    __syncthreads();

    for (int r = wv; r < 24; r += 4) {
        int n2 = blockIdx.x * 24 + r;
        if (n2 >= NN) continue;
        float v = (lane < OUTD) ? svals[r][lane] : -1e30f;
        float mx = v;
#pragma unroll
        for (int o = 32; o; o >>= 1) mx = fmaxf(mx, __shfl_xor(mx, o));
        float ex = (lane < OUTD) ? __expf(v - mx) : 0.f;
        float sm = ex;
#pragma unroll
        for (int o = 32; o; o >>= 1) sm += __shfl_xor(sm, o);
        if (lane < OUTD) out[(size_t)n2 * OUTD + lane] = v - mx - __logf(sm);
    }
}

// ----------------------------------------------------------------
extern "C" void kernel_launch(void* const* d_in, const int* in_sizes, int n_in,
                              void* d_out, int out_size, void* d_ws, size_t ws_size,
                              hipStream_t stream)
{
    const float* x   = (const float*)d_in[0];
    const int*   ei  = (const int*)  d_in[1];
    const float* W1  = (const float*)d_in[2];
    const float* as1 = (const float*)d_in[3];
    const float* ad1 = (const float*)d_in[4];
    const float* b1  = (const float*)d_in[5];
    const float* W2  = (const float*)d_in[6];
    const float* as2 = (const float*)d_in[7];
    const float* ad2 = (const float*)d_in[8];
    const float* b2  = (const float*)d_in[9];
    float* out = (float*)d_out;

    // flat workspace layout (~19 MB; epack/esrc/off retired, nlist slab added)
    char* ws = (char*)d_ws;
    __half* h1h   = (__half*)(ws);                        //  6,400,000 B
    __half* h2h   = (__half*)(ws +  6400000);             //  4,000,000 B
    float*  asrc1 = (float*) (ws + 10400000);             //    800,000 B
    float*  adst1 = (float*) (ws + 11200000);             //    800,000 B
    float*  asrc2 = (float*) (ws + 12000000);             //    200,000 B
    float*  adst2 = (float*) (ws + 12200000);             //    200,000 B
    u16*    nlist = (u16*)   (ws + 12400000);             //  6,400,000 B (NN*NCAP*2)
    int*    ncur  = (int*)   (ws + 18800000);             //    200,000 B

    hipMemsetAsync(ncur, 0, NN * sizeof(int), stream);
    hipLaunchKernelGGL(k_binG1,  dim3(BINB + G1B), dim3(256), 0, stream,
                       ei, ncur, nlist, x, W1, as1, ad1, h1h, asrc1, adst1);
    hipLaunchKernelGGL(k_fagg1g2, dim3(3125), dim3(256), 0, stream,
                       ncur, nlist, asrc1, adst1, h1h, b1, W2, as2, ad2, h2h, asrc2, adst2);
    hipLaunchKernelGGL(k_fagg2,  dim3(2084), dim3(256), 0, stream,
                       ncur, nlist, asrc2, adst2, h2h, b2, out);
}

// Round 12
// 178.623 us; speedup vs baseline: 1.1564x; 1.1564x over previous
//
#include <hip/hip_runtime.h>
#include <hip/hip_fp16.h>
#include <math.h>

#define NN    50000
#define NE0   800000
#define NE    850000
#define INDIM 128
#define HID   64
#define OUTD  40

#define NB    391          // ceil(50000/128) buckets of 128 dsts
#define BSH   7            // bucket shift (dst >> 7)
#define BCAP  3072         // per-bucket capacity (max load ~2400)

#define BINB  256          // bin role blocks
#define G1B   782          // gemm1 role blocks

typedef unsigned short u16;

// ---------------------------------------------------------------- dispatch A: bin (blocks 0..255) || GEMM1 (blocks 256..1037)
// R7-proven: x staged in LDS (cold-stream latency amortization), W1 direct
// (L1-hot broadcast). 4 blocks/CU.
union __align__(16) SMa {
    float xs[64 * 132];                                             // 33.8 KB
    struct { int lh[NB]; int lbase[NB]; unsigned ebuf[3328]; } b;   // 16.4 KB
};

__global__ __launch_bounds__(256, 4) void k_binG1(
    const int* __restrict__ ei, int* __restrict__ bcur, unsigned int* __restrict__ epack,
    const float* __restrict__ x, const float* __restrict__ W1,
    const float* __restrict__ a_s, const float* __restrict__ a_d,
    __half* __restrict__ h1h, float* __restrict__ asrc1, float* __restrict__ adst1)
{
    __shared__ SMa sm;
    const int tid = threadIdx.x;

    if (blockIdx.x < BINB) {
        // ---------------- bin role (R5/R7 verbatim) ----------------
        const int CH = (NE + BINB - 1) / BINB;     // 3321
        const int e0 = blockIdx.x * CH;
        const int e1 = (e0 + CH < NE) ? e0 + CH : NE;
        const int cnt = e1 - e0;

        for (int i = tid; i < NB; i += 256) sm.b.lh[i] = 0;
        __syncthreads();
        for (int i = tid; i < cnt; i += 256) {
            int e = e0 + i;
            int src, dst;
            if (e < NE0) { src = ei[e]; dst = ei[NE0 + e]; }
            else         { src = e - NE0; dst = src; }
            int bkt = dst >> BSH;
            sm.b.ebuf[i] = (unsigned)src | ((unsigned)(dst & 127) << 16) | ((unsigned)bkt << 23);
            atomicAdd(&sm.b.lh[bkt], 1);
        }
        __syncthreads();
        for (int i = tid; i < NB; i += 256) {
            int c = sm.b.lh[i];
            sm.b.lbase[i] = c ? (i * BCAP + atomicAdd(&bcur[i], c)) : 0;
            sm.b.lh[i] = 0;
        }
        __syncthreads();
        for (int i = tid; i < cnt; i += 256) {
            unsigned rec = sm.b.ebuf[i];
            int bkt = rec >> 23;
            int lpos = atomicAdd(&sm.b.lh[bkt], 1);
            epack[sm.b.lbase[bkt] + lpos] = rec & 0x7FFFFFu;
        }
        return;
    }

    // ---------------- GEMM1 role: x staged in LDS, W1 direct (L1-hot) ----------------
    const int r0 = (blockIdx.x - BINB) * 64;

    const float4* x4 = (const float4*)x;
#pragma unroll
    for (int i = 0; i < 8; ++i) {
        int idx = tid + i * 256;           // 0..2047
        int row = idx >> 5;                // 32 float4 per row
        int k4  = idx & 31;
        int nr = r0 + row;
        float4 v = make_float4(0.f, 0.f, 0.f, 0.f);
        if (nr < NN) v = x4[(size_t)nr * 32 + k4];
        *(float4*)&sm.xs[row * 132 + k4 * 4] = v;
    }
    __syncthreads();

    const int rg = tid >> 4;               // 0..15 (4 rows each)
    const int cg = tid & 15;
    const int c4 = cg * 4;
    const float as0 = a_s[c4], as1v = a_s[c4+1], as2v = a_s[c4+2], as3v = a_s[c4+3];
    const float ad0 = a_d[c4], ad1v = a_d[c4+1], ad2v = a_d[c4+2], ad3v = a_d[c4+3];

    float acc[4][4];
#pragma unroll
    for (int i = 0; i < 4; ++i)
#pragma unroll
        for (int j = 0; j < 4; ++j) acc[i][j] = 0.f;

#pragma unroll 4
    for (int k4 = 0; k4 < 32; ++k4) {
        float4 xv[4];
#pragma unroll
        for (int i = 0; i < 4; ++i)
            xv[i] = *(const float4*)&sm.xs[(rg * 4 + i) * 132 + k4 * 4];
        const float* wp = &W1[(k4 * 4) * HID + c4];
        float4 w0 = *(const float4*)(wp);
        float4 w1 = *(const float4*)(wp + HID);
        float4 w2 = *(const float4*)(wp + 2 * HID);
        float4 w3 = *(const float4*)(wp + 3 * HID);
#pragma unroll
        for (int i = 0; i < 4; ++i) {
            acc[i][0] += xv[i].x * w0.x + xv[i].y * w1.x + xv[i].z * w2.x + xv[i].w * w3.x;
            acc[i][1] += xv[i].x * w0.y + xv[i].y * w1.y + xv[i].z * w2.y + xv[i].w * w3.y;
            acc[i][2] += xv[i].x * w0.z + xv[i].y * w1.z + xv[i].z * w2.z + xv[i].w * w3.z;
            acc[i][3] += xv[i].x * w0.w + xv[i].y * w1.w + xv[i].z * w2.w + xv[i].w * w3.w;
        }
    }

#pragma unroll
    for (int i = 0; i < 4; ++i) {
        const int n = r0 + rg * 4 + i;
        if (n < NN) {
            __half2 ha = __floats2half2_rn(acc[i][0], acc[i][1]);
            __half2 hb = __floats2half2_rn(acc[i][2], acc[i][3]);
            *(__half2*)&h1h[(size_t)n * HID + c4]     = ha;
            *(__half2*)&h1h[(size_t)n * HID + c4 + 2] = hb;
        }
        float ps = acc[i][0] * as0 + acc[i][1] * as1v + acc[i][2] * as2v + acc[i][3] * as3v;
        float pd = acc[i][0] * ad0 + acc[i][1] * ad1v + acc[i][2] * ad2v + acc[i][3] * ad3v;
        ps += __shfl_xor(ps, 1); ps += __shfl_xor(ps, 2);
        pd += __shfl_xor(pd, 1); pd += __shfl_xor(pd, 2);
        if ((cg & 3) == 0 && n < NN) {
            int head = cg >> 2;
            asrc1[n * 4 + head] = ps;
            adst1[n * 4 + head] = pd;
        }
    }
}

// ---------------------------------------------------------------- per-bucket fine CSR: 512 threads/block (8 waves; was 4)
// Same algorithm as R7; doubled wave-parallelism halves the per-thread
// serial scan+scatter chain and doubles resident waves/CU.
__global__ __launch_bounds__(512) void k_csr(
    const int* __restrict__ bcur, const unsigned int* __restrict__ epack,
    int* __restrict__ off_s, int* __restrict__ off_e, u16* __restrict__ esrc)
{
    __shared__ int lh[128];
    __shared__ int lcur[128];
    __shared__ int sblk;
    const int tid = threadIdx.x, lane = tid & 63;
    const int b = blockIdx.x;
    const int e0 = b * BCAP;
    const int cnt = bcur[b];                   // zero-based count

    if (tid < 128) lh[tid] = 0;
    __syncthreads();
    for (int i = tid; i < cnt; i += 512)
        atomicAdd(&lh[epack[e0 + i] >> 16], 1);
    __syncthreads();

    int v = 0, incl = 0;
    if (tid < 128) {
        v = lh[tid];
        incl = v;
#pragma unroll
        for (int s = 1; s < 64; s <<= 1) {
            int t = __shfl_up(incl, s);
            if (lane >= s) incl += t;
        }
    }
    if (tid == 63) sblk = incl;
    __syncthreads();
    if (tid >= 64 && tid < 128) incl += sblk;
    if (tid < 128) {
        int ex = e0 + incl - v;
        lcur[tid] = ex;
        int gd = b * 128 + tid;
        if (gd < NN) { off_s[gd] = ex; off_e[gd] = ex + v; }
    }
    __syncthreads();

    for (int i = tid; i < cnt; i += 512) {
        unsigned int p = epack[e0 + i];
        int pos = atomicAdd(&lcur[p >> 16], 1);
        esrc[pos] = (u16)(p & 0xFFFFu);
    }
}

// ---------------------------------------------------------------- layer-1 aggregate fused with GEMM2 (R7 verbatim)
__global__ __launch_bounds__(256) void k_fagg1g2(
    const int* __restrict__ off_s, const int* __restrict__ off_e,
    const u16* __restrict__ esrc, const float* __restrict__ asrc1,
    const float* __restrict__ adst1,
    const __half* __restrict__ h1h, const float* __restrict__ b1,
    const float* __restrict__ W2, const float* __restrict__ a_s2,
    const float* __restrict__ a_d2,
    __half* __restrict__ h2h, float* __restrict__ asrc2, float* __restrict__ adst2)
{
    __shared__ __align__(16) float W2l[HID * OUTD];   // 10.2 KB
    __shared__ __align__(16) float hml[16][72];       // stride 72 (16B-aligned rows)
    __shared__ float s_a2s[OUTD], s_a2d[OUTD];
    __shared__ float s_ps[16], s_pd[16];
    const int tid = threadIdx.x;

    {
        const float4* W24 = (const float4*)W2;
        float4* W2l4 = (float4*)W2l;
        for (int i = tid; i < (HID * OUTD) / 4; i += 256) W2l4[i] = W24[i];
        if (tid < OUTD) { s_a2s[tid] = a_s2[tid]; s_a2d[tid] = a_d2[tid]; }
        if (tid < 16)   { s_ps[tid] = 0.f; s_pd[tid] = 0.f; }
    }

    const int wv = tid >> 6, lane = tid & 63;
    const int g = lane >> 4, li = lane & 15;      // 4 nodes/wave, 16 lanes each
    const int r = wv * 4 + g;                     // 0..15 node slot in block
    const int n = blockIdx.x * 16 + r;            // grid exact: 3125*16 = 50000
    const int s0 = off_s[n], s1 = off_e[n];
    const int hp = li >> 2;                       // head
    const float adst = adst1[n * 4 + hp];
    const int last = s1 - 1;                      // deg >= 1 (self-loop)

    float l = 0.f, a0 = 0.f, a1 = 0.f, a2 = 0.f, a3 = 0.f;
    const char* hb = (const char*)h1h;

    int sxA[8];
#pragma unroll
    for (int j = 0; j < 8; ++j) {
        int ix = s0 + j;
        sxA[j] = esrc[ix < s1 ? ix : last];
    }
    for (int t = s0; t < s1; t += 8) {
        float ax[8];
#pragma unroll
        for (int j = 0; j < 8; ++j) ax[j] = asrc1[sxA[j] * 4 + hp];
        uint2 raw[8];
#pragma unroll
        for (int j = 0; j < 8; ++j)
            raw[j] = *(const uint2*)(hb + ((size_t)sxA[j] * 128 + li * 8));
        int sxB[8];
        const int t2 = t + 8;
#pragma unroll
        for (int j = 0; j < 8; ++j) {
            int ix = t2 + j;
            sxB[j] = esrc[ix < s1 ? ix : last];
        }
#pragma unroll
        for (int j = 0; j < 8; ++j) {
            float e = ax[j] + adst;
            e = (e > 0.f) ? e : 0.2f * e;
            float w = __expf(e);
            w = ((t + j) < s1) ? w : 0.f;
            float2 f0 = __half22float2(*(__half2*)&raw[j].x);
            float2 f1 = __half22float2(*(__half2*)&raw[j].y);
            l  += w;
            a0 += w * f0.x;
            a1 += w * f0.y;
            a2 += w * f1.x;
            a3 += w * f1.y;
        }
#pragma unroll
        for (int j = 0; j < 8; ++j) sxA[j] = sxB[j];
    }

    {
        float rcp = 1.f / l;
        float4 bv = *(const float4*)&b1[li * 4];
        float o0 = fmaxf(a0 * rcp + bv.x, 0.f);
        float o1 = fmaxf(a1 * rcp + bv.y, 0.f);
        float o2 = fmaxf(a2 * rcp + bv.z, 0.f);
        float o3 = fmaxf(a3 * rcp + bv.w, 0.f);
        *(float4*)&hml[r][li * 4] = make_float4(o0, o1, o2, o3);
    }
    __syncthreads();

    // mini-GEMM: 16x64 @ 64x40; 160 threads, one output quad each
    if (tid < 160) {
        const int rr = tid / 10;                  // 0..15
        const int c4 = (tid - rr * 10) * 4;       // 0..36
        float4 acc = make_float4(0.f, 0.f, 0.f, 0.f);
#pragma unroll 4
        for (int k4 = 0; k4 < 16; ++k4) {
            float4 hv = *(const float4*)&hml[rr][k4 * 4];
            const float* wp = &W2l[(k4 * 4) * OUTD + c4];
            float4 w0 = *(const float4*)(wp);
            float4 w1 = *(const float4*)(wp + OUTD);
            float4 w2 = *(const float4*)(wp + 2 * OUTD);
            float4 w3 = *(const float4*)(wp + 3 * OUTD);
            acc.x += hv.x * w0.x + hv.y * w1.x + hv.z * w2.x + hv.w * w3.x;
            acc.y += hv.x * w0.y + hv.y * w1.y + hv.z * w2.y + hv.w * w3.y;
            acc.z += hv.x * w0.z + hv.y * w1.z + hv.z * w2.z + hv.w * w3.z;
            acc.w += hv.x * w0.w + hv.y * w1.w + hv.z * w2.w + hv.w * w3.w;
        }
        const int n2 = blockIdx.x * 16 + rr;
        __half2 ha = __floats2half2_rn(acc.x, acc.y);
        __half2 hc = __floats2half2_rn(acc.z, acc.w);
        uint2 st;
        st.x = *(unsigned*)&ha;
        st.y = *(unsigned*)&hc;
        *(uint2*)((char*)h2h + ((size_t)n2 * 80 + c4 * 2)) = st;
        float ps = acc.x * s_a2s[c4] + acc.y * s_a2s[c4 + 1] + acc.z * s_a2s[c4 + 2] + acc.w * s_a2s[c4 + 3];
        float pd = acc.x * s_a2d[c4] + acc.y * s_a2d[c4 + 1] + acc.z * s_a2d[c4 + 2] + acc.w * s_a2d[c4 + 3];
        atomicAdd(&s_ps[rr], ps);
        atomicAdd(&s_pd[rr], pd);
    }
    __syncthreads();
    if (tid < 16) {
        const int n2 = blockIdx.x * 16 + tid;
        asrc2[n2] = s_ps[tid];
        adst2[n2] = s_pd[tid];
    }
}

// ---------------------------------------------------------------- layer-2 aggregate: 10 lanes/node, 6 nodes/wave, LDS log_softmax (R7 verbatim)
__global__ __launch_bounds__(256) void k_fagg2(
    const int* __restrict__ off_s, const int* __restrict__ off_e,
    const u16* __restrict__ esrc, const float* __restrict__ asrc2,
    const float* __restrict__ adst2,
    const __half* __restrict__ h2h, const float* __restrict__ b2,
    float* __restrict__ out)
{
    __shared__ float svals[24][OUTD];
    const int wv = threadIdx.x >> 6, lane = threadIdx.x & 63;
    const int g = lane / 10;                       // 0..6 (g==6 idle)
    const int li = lane - g * 10;                  // 0..9
    const bool ga = (g < 6);
    const int n = blockIdx.x * 24 + wv * 6 + (ga ? g : 0);
    const bool valid = ga && (n < NN);
    const int s0 = valid ? off_s[n] : 0;
    const int s1 = valid ? off_e[n] : 0;
    const float adst = valid ? adst2[n] : 0.f;
    const int last = (s1 > 0) ? s1 - 1 : 0;

    float l = 0.f, a0 = 0.f, a1 = 0.f, a2 = 0.f, a3 = 0.f;
    const char* hb = (const char*)h2h;

    int sxA[8];
#pragma unroll
    for (int j = 0; j < 8; ++j) {
        int ix = s0 + j;
        sxA[j] = esrc[ix < s1 ? ix : last];
    }
    for (int t = s0; t < s1; t += 8) {
        float ax[8];
#pragma unroll
        for (int j = 0; j < 8; ++j) ax[j] = asrc2[sxA[j]];
        uint2 raw[8];
#pragma unroll
        for (int j = 0; j < 8; ++j)
            raw[j] = *(const uint2*)(hb + ((size_t)sxA[j] * 80 + li * 8));
        int sxB[8];
        const int t2 = t + 8;
#pragma unroll
        for (int j = 0; j < 8; ++j) {
            int ix = t2 + j;
            sxB[j] = esrc[ix < s1 ? ix : last];
        }
#pragma unroll
        for (int j = 0; j < 8; ++j) {
            float e = ax[j] + adst;
            e = (e > 0.f) ? e : 0.2f * e;
            float w = __expf(e);
            w = ((t + j) < s1) ? w : 0.f;
            float2 f0 = __half22float2(*(__half2*)&raw[j].x);
            float2 f1 = __half22float2(*(__half2*)&raw[j].y);
            l  += w;
            a0 += w * f0.x;
            a1 += w * f0.y;
            a2 += w * f1.x;
            a3 += w * f1.y;
        }
#pragma unroll
        for (int j = 0; j < 8; ++j) sxA[j] = sxB[j];
    }
    if (valid) {
        float rcp = 1.f / l;
        float4 bv = *(const float4*)&b2[li * 4];
        int r = wv * 6 + g;
        svals[r][li * 4]     = a0 * rcp + bv.x;
        svals[r][li * 4 + 1] = a1 * rcp + bv.y;
        svals[r][li * 4 + 2] = a2 * rcp + bv.z;
        svals[r][li * 4 + 3] = a3 * rcp + bv.w;
    }
    __syncthreads();

    for (int r = wv; r < 24; r += 4) {
        int n2 = blockIdx.x * 24 + r;
        if (n2 >= NN) continue;
        float v = (lane < OUTD) ? svals[r][lane] : -1e30f;
        float mx = v;
#pragma unroll
        for (int o = 32; o; o >>= 1) mx = fmaxf(mx, __shfl_xor(mx, o));
        float ex = (lane < OUTD) ? __expf(v - mx) : 0.f;
        float sm = ex;
#pragma unroll
        for (int o = 32; o; o >>= 1) sm += __shfl_xor(sm, o);
        if (lane < OUTD) out[(size_t)n2 * OUTD + lane] = v - mx - __logf(sm);
    }
}

// ----------------------------------------------------------------
extern "C" void kernel_launch(void* const* d_in, const int* in_sizes, int n_in,
                              void* d_out, int out_size, void* d_ws, size_t ws_size,
                              hipStream_t stream)
{
    const float* x   = (const float*)d_in[0];
    const int*   ei  = (const int*)  d_in[1];
    const float* W1  = (const float*)d_in[2];
    const float* as1 = (const float*)d_in[3];
    const float* ad1 = (const float*)d_in[4];
    const float* b1  = (const float*)d_in[5];
    const float* W2  = (const float*)d_in[6];
    const float* as2 = (const float*)d_in[7];
    const float* ad2 = (const float*)d_in[8];
    const float* b2  = (const float*)d_in[9];
    float* out = (float*)d_out;

    // flat workspace layout (~20 MB)
    char* ws = (char*)d_ws;
    __half* h1h   = (__half*)(ws);                        //  6,400,000 B
    __half* h2h   = (__half*)(ws +  6400000);             //  4,000,000 B
    float*  asrc1 = (float*) (ws + 10400000);             //    800,000 B
    float*  adst1 = (float*) (ws + 11200000);             //    800,000 B
    float*  asrc2 = (float*) (ws + 12000000);             //    200,000 B
    float*  adst2 = (float*) (ws + 12200000);             //    200,000 B
    int*    off_s = (int*)   (ws + 12400000);             //    200,000 B
    int*    off_e = (int*)   (ws + 12600000);             //    200,000 B
    unsigned int* epack = (unsigned int*)(ws + 12800000); //  4,804,608 B (NB*BCAP*4)
    u16*    esrc  = (u16*)   (ws + 17604608);             //  2,402,304 B (NB*BCAP*2)
    int*    bcur  = (int*)   (ws + 20006912);             //      1,564 B

    hipMemsetAsync(bcur, 0, NB * sizeof(int), stream);
    hipLaunchKernelGGL(k_binG1,  dim3(BINB + G1B), dim3(256), 0, stream,
                       ei, bcur, epack, x, W1, as1, ad1, h1h, asrc1, adst1);
    hipLaunchKernelGGL(k_csr,    dim3(NB),   dim3(512), 0, stream,
                       bcur, epack, off_s, off_e, esrc);
    hipLaunchKernelGGL(k_fagg1g2, dim3(3125), dim3(256), 0, stream,
                       off_s, off_e, esrc, asrc1, adst1, h1h, b1, W2, as2, ad2, h2h, asrc2, adst2);
    hipLaunchKernelGGL(k_fagg2,  dim3(2084), dim3(256), 0, stream,
                       off_s, off_e, esrc, asrc2, adst2, h2h, b2, out);
}